// Round 7
// baseline (152.969 us; speedup 1.0000x reference)
//
#include <hip/hip_runtime.h>

#define NN 8192
#define EE 256
#define KNH 32
#define NKEEP 4096
#define NB 512

typedef unsigned long long u64;
typedef unsigned int u32;

// ws layout:
// part   @ 0      [2][32][256] f32   (65536)
// gm     @ 65536  [2][256] f32       ( 2048)
// bincnt @ 67584  [2][512] int       ( 4096)
// start  @ 71680  [2][513] int       ( 4224 alloc)
// fill   @ 75904  [2][512] int       ( 4096)
// sc     @ 80000  [2][8192] float2   (131072)
// sj     @ 211072 [2][8192] int      ( 65536)  -> 276608 total

__device__ __forceinline__ int binof(float v) {
    const int q = (int)floorf((v + 4.6f) * (512.0f / 9.2f));
    return min(max(q, 0), NB - 1);
}

__global__ void k_gm_partial(const float* __restrict__ x, float* __restrict__ part) {
    const int b = blockIdx.y, chunk = blockIdx.x, t = threadIdx.x;
    const float* xp = x + ((size_t)b * NN + (size_t)chunk * 256) * EE + t;
    float s = 0.0f;
    for (int i = 0; i < 256; ++i) s += xp[(size_t)i * EE];
    part[((size_t)b * 32 + chunk) * EE + t] = s;
}

__global__ void k_gm_final(const float* __restrict__ part, float* __restrict__ gm) {
    const int b = blockIdx.y, t = threadIdx.x;
    float s = 0.0f;
    for (int c = 0; c < 32; ++c) s += part[((size_t)b * 32 + c) * EE + t];
    gm[b * EE + t] = fabsf(s / (float)NN);
}

__global__ void k_bin_count(const float* __restrict__ coords, int* __restrict__ bincnt) {
    const int b = blockIdx.y;
    const int i = blockIdx.x * 256 + threadIdx.x;
    const float xv = coords[(size_t)b * 2 * NN + i];
    atomicAdd(&bincnt[b * NB + binof(xv)], 1);
}

__global__ void k_bin_scan(const int* __restrict__ bincnt, int* __restrict__ start,
                           int* __restrict__ fill) {
    __shared__ int sdata[NB];
    const int b = blockIdx.x, t = threadIdx.x;
    const int v = bincnt[b * NB + t];
    sdata[t] = v;
    __syncthreads();
    for (int d = 1; d < NB; d <<= 1) {
        const int add = (t >= d) ? sdata[t - d] : 0;
        __syncthreads();
        sdata[t] += add;
        __syncthreads();
    }
    const int incl = sdata[t];
    const int excl = incl - v;
    start[b * (NB + 1) + t] = excl;
    fill[b * NB + t] = excl;
    if (t == NB - 1) start[b * (NB + 1) + NB] = incl;
}

__global__ void k_scatter(const float* __restrict__ coords, int* __restrict__ fill,
                          float2* __restrict__ sc, int* __restrict__ sj) {
    const int b = blockIdx.y;
    const int i = blockIdx.x * 256 + threadIdx.x;
    const float xv = coords[(size_t)b * 2 * NN + i];
    const float yv = coords[(size_t)b * 2 * NN + NN + i];
    const int p = atomicAdd(&fill[b * NB + binof(xv)], 1);
    sc[(size_t)b * NN + p] = make_float2(xv, yv);
    sj[(size_t)b * NN + p] = i;
}

__device__ __forceinline__ u64 shfl_xor_u64(u64 v, int m) {
    const u32 hi = (u32)__shfl_xor((int)(u32)(v >> 32), m);
    const u32 lo = (u32)__shfl_xor((int)(u32)v, m);
    return ((u64)hi << 32) | lo;
}

__device__ __forceinline__ u64 wave_min_u64(u64 h) {
#pragma unroll
    for (int s = 1; s < 64; s <<= 1) {
        const u64 o = shfl_xor_u64(h, s);
        h = (o < h) ? o : h;
    }
    return h;
}

// One wave per point.
// Pass 1: full-scan per-lane MIN distance; T = 32nd smallest of the 64 minima
// (u32 bitonic sort) — a valid upper bound on d32 (32 minima = 32 distinct cands).
// Range: d<=T => |dx|<=sqrt(T) => contiguous x-bin scatter range (~130-700 cands).
// Pass 2: scan range, survivors (d<=T) into per-lane LDS slots; lane-offset
// compaction; u64 bitonic sort -> exact top-32 by (d_bits, orig_j).
// Certificates (total>64 | lane cnt>8 | total<32) -> exact range argmin fallback.
__global__ void k_knn_dist(const float* __restrict__ x, const float* __restrict__ coords,
                           const float* __restrict__ gm, const float2* __restrict__ sc,
                           const int* __restrict__ sj, const int* __restrict__ start,
                           float* __restrict__ ld_out) {
    __shared__ u64 slots[4][512];
    __shared__ u64 comp[4][64];
    const int b    = blockIdx.y;
    const int wid  = threadIdx.x >> 6;
    const int lane = threadIdx.x & 63;
    const int i    = blockIdx.x * 4 + wid;

    const float* cs0 = coords + (size_t)b * 2 * NN;
    const float* cs1 = cs0 + NN;
    const float ci0 = cs0[i];
    const float ci1 = cs1[i];

    // ---- pass 1: per-lane min distance over all 8192 ----
    float dmin = 1e30f;
#pragma unroll 4
    for (int t = 0; t < NN / 256; ++t) {
        const int j = t * 256 + (lane << 2);
        const float4 xa = *reinterpret_cast<const float4*>(cs0 + j);
        const float4 ya = *reinterpret_cast<const float4*>(cs1 + j);
        const float dx0 = ci0 - xa.x, dy0 = ci1 - ya.x;
        const float dx1 = ci0 - xa.y, dy1 = ci1 - ya.y;
        const float dx2 = ci0 - xa.z, dy2 = ci1 - ya.z;
        const float dx3 = ci0 - xa.w, dy3 = ci1 - ya.w;
        const float d0 = fmaf(dx0, dx0, dy0 * dy0);
        const float d1 = fmaf(dx1, dx1, dy1 * dy1);
        const float d2 = fmaf(dx2, dx2, dy2 * dy2);
        const float d3 = fmaf(dx3, dx3, dy3 * dy3);
        dmin = fminf(dmin, fminf(fminf(d0, d1), fminf(d2, d3)));
    }

    // ---- T = 32nd smallest of the 64 lane minima (u32 bitonic sort) ----
    u32 mk = __float_as_uint(dmin);
#pragma unroll
    for (int k = 2; k <= 64; k <<= 1) {
#pragma unroll
        for (int j = k >> 1; j > 0; j >>= 1) {
            const u32 o = (u32)__shfl_xor((int)mk, j);
            const bool keep_min = (((lane & j) == 0) == ((lane & k) == 0));
            const u32 mn = min(mk, o), mx = max(mk, o);
            mk = keep_min ? mn : mx;
        }
    }
    const u32 T = (u32)__shfl((int)mk, 31);

    // ---- candidate range from x-bins ----
    const float s = sqrtf(__uint_as_float(T)) * 1.0002f;
    const int bl = max(binof(ci0 - s) - 1, 0);
    const int bh = min(binof(ci0 + s) + 1, NB - 1);
    const int c0 = start[b * (NB + 1) + bl];
    const int c1 = start[b * (NB + 1) + bh + 1];
    const float2* scb = sc + (size_t)b * NN;
    const int*    sjb = sj + (size_t)b * NN;

    // ---- pass 2: survivors into per-lane slots ----
    int cnt = 0;
    for (int t0 = c0; t0 < c1; t0 += 64) {
        const int c = t0 + lane;
        const int cc = min(c, NN - 1);
        const float2 p = scb[cc];
        const int    jj = sjb[cc];
        const float dx = ci0 - p.x, dy = ci1 - p.y;
        const u32 db = __float_as_uint(fmaf(dx, dx, dy * dy));
        const bool keep = (c < c1) && (db <= T);
        if (keep) {
            slots[wid][(lane << 3) + (cnt & 7)] = ((u64)db << 32) | (u32)jj;
            ++cnt;
        }
    }

    // ---- compact: exclusive scan of per-lane counts ----
    const int myc = min(cnt, 8);
    int scn = myc;
#pragma unroll
    for (int d = 1; d < 64; d <<= 1) {
        const int v = __shfl_up(scn, d);
        scn += (lane >= d) ? v : 0;
    }
    const int off   = scn - myc;
    const int total = __shfl(scn, 63);
    const bool ovf  = (total > 64) || (total < KNH) || __any(cnt > 8);

    for (int c2 = 0; c2 < myc; ++c2) {
        comp[wid][(off + c2) & 63] = slots[wid][(lane << 3) + c2];
    }
    __syncthreads();

    // ---- bitonic sort (ascending) of up to 64 survivor keys ----
    u64 key = (lane < total) ? comp[wid][lane] : ~0ull;
#pragma unroll
    for (int k = 2; k <= 64; k <<= 1) {
#pragma unroll
        for (int j = k >> 1; j > 0; j >>= 1) {
            const u64 other = shfl_xor_u64(key, j);
            const bool keep_min = (((lane & j) == 0) == ((lane & k) == 0));
            const bool lt = (key < other);
            const u64 mn = lt ? key : other;
            const u64 mx = lt ? other : key;
            key = keep_min ? mn : mx;
        }
    }
    int jkeep = (int)(u32)key;   // lane m (m<32) holds m-th nearest index

    // ---- certificate fallback: exact 32-round argmin over the range ----
    if (ovf) {
        u64 minkeep = 0;
        for (int k = 0; k < KNH; ++k) {
            u64 best = ~0ull;
            for (int t0 = c0; t0 < c1; t0 += 64) {
                const int c = t0 + lane;
                const int cc = min(c, NN - 1);
                const float2 p = scb[cc];
                const int    jj = sjb[cc];
                const float dx = ci0 - p.x, dy = ci1 - p.y;
                const float d  = fmaf(dx, dx, dy * dy);
                const u64 kk = ((u64)__float_as_uint(d) << 32) | (u32)jj;
                if (c < c1 && kk >= minkeep && kk < best) best = kk;
            }
            const u64 h = wave_min_u64(best);
            if (lane == k) jkeep = (int)(u32)h;
            minkeep = h + 1;
        }
    }

    // ---- gather 32 rows, f32 sum/sumsq (4 channels per lane) ----
    float s1[4] = {0.f, 0.f, 0.f, 0.f};
    float s2[4] = {0.f, 0.f, 0.f, 0.f};
    const float* xb = x + (size_t)b * NN * EE;
#pragma unroll 8
    for (int k = 0; k < KNH; ++k) {
        const int j = __shfl(jkeep, k);
        const float4 v = *reinterpret_cast<const float4*>(xb + (size_t)j * EE + (lane << 2));
        s1[0] += v.x; s2[0] += v.x * v.x;
        s1[1] += v.y; s2[1] += v.y * v.y;
        s1[2] += v.z; s2[2] += v.z * v.z;
        s1[3] += v.w; s2[3] += v.w * v.w;
    }

    const float* gmb = gm + b * EE;
    float tt = 0.f;
#pragma unroll
    for (int q = 0; q < 4; ++q) {
        const float sum = s1[q];
        float ssd = s2[q] - sum * sum * (1.0f / 32.0f);
        ssd = ssd > 0.f ? ssd : 0.f;
        const float ls = sqrtf(ssd * (1.0f / 31.0f));
        tt += ls / gmb[(lane << 2) + q];
    }
#pragma unroll
    for (int s2r = 1; s2r < 64; s2r <<= 1) tt += __shfl_xor(tt, s2r);

    if (lane == 0) ld_out[(size_t)b * NN + i] = tt;
}

// one wave per point: exact rank (desc, index tie-break) + direct row gather
__global__ void k_rank_gather(const float* __restrict__ x, const float* __restrict__ coords,
                              const float* __restrict__ ld,
                              float* __restrict__ x_out, float* __restrict__ c_out) {
    const int b    = blockIdx.y;
    const int wid  = threadIdx.x >> 6;
    const int lane = threadIdx.x & 63;
    const int i    = blockIdx.x * 4 + wid;
    const float* lb = ld + (size_t)b * NN;
    const float di = lb[i];
    int cnt = 0;
    for (int t = 0; t < NN / 64; ++t) {
        const int j = lane + t * 64;
        const float dj = lb[j];
        cnt += (dj > di || (dj == di && j < i)) ? 1 : 0;
    }
#pragma unroll
    for (int s = 1; s < 64; s <<= 1) cnt += __shfl_xor(cnt, s);

    if (cnt < NKEEP) {
        const float4 v = *reinterpret_cast<const float4*>(x + ((size_t)b * NN + i) * EE + (lane << 2));
        *reinterpret_cast<float4*>(x_out + ((size_t)b * NKEEP + cnt) * EE + (lane << 2)) = v;
        if (lane < 2) {
            c_out[((size_t)b * 2 + lane) * NKEEP + cnt] = coords[((size_t)b * 2 + lane) * NN + i];
        }
    }
}

extern "C" void kernel_launch(void* const* d_in, const int* in_sizes, int n_in,
                              void* d_out, int out_size, void* d_ws, size_t ws_size,
                              hipStream_t stream) {
    const float* x      = (const float*)d_in[0];
    const float* coords = (const float*)d_in[1];

    float* out    = (float*)d_out;
    float* x_out  = out;                 // [2][4096][256]
    float* c_out  = out + 2097152;       // [2][2][4096][1]
    float* ld_out = out + 2113536;       // [2][8192]

    char*   ws     = (char*)d_ws;
    float*  part   = (float*)(ws);
    float*  gm     = (float*)(ws + 65536);
    int*    bincnt = (int*)  (ws + 67584);
    int*    start  = (int*)  (ws + 71680);
    int*    fill   = (int*)  (ws + 75904);
    float2* sc     = (float2*)(ws + 80000);
    int*    sj     = (int*)  (ws + 211072);

    hipMemsetAsync(bincnt, 0, 2 * NB * sizeof(int), stream);
    k_gm_partial <<<dim3(32, 2),   256, 0, stream>>>(x, part);
    k_gm_final   <<<dim3(1, 2),    256, 0, stream>>>(part, gm);
    k_bin_count  <<<dim3(32, 2),   256, 0, stream>>>(coords, bincnt);
    k_bin_scan   <<<2,             NB,  0, stream>>>(bincnt, start, fill);
    k_scatter    <<<dim3(32, 2),   256, 0, stream>>>(coords, fill, sc, sj);
    k_knn_dist   <<<dim3(2048, 2), 256, 0, stream>>>(x, coords, gm, sc, sj, start, ld_out);
    k_rank_gather<<<dim3(2048, 2), 256, 0, stream>>>(x, coords, ld_out, x_out, c_out);
}